// Round 13
// baseline (466.572 us; speedup 1.0000x reference)
//
#include <hip/hip_runtime.h>
#include <hip/hip_bf16.h>
#include <cstdint>
#include <cstddef>

using bf16 = __hip_bfloat16;
typedef __attribute__((ext_vector_type(8))) short short8;
typedef __attribute__((ext_vector_type(4))) short short4v;
typedef __attribute__((ext_vector_type(4))) float f32x4;

#define MFMA16(a,b,c) __builtin_amdgcn_mfma_f32_16x16x32_bf16((a),(b),(c),0,0,0)
#define VMWAIT(n) asm volatile("s_waitcnt vmcnt(" #n ")" ::: "memory")

constexpr int S  = 2048;
constexpr int H  = 4096;
constexpr int D  = 128;

static __device__ __forceinline__ short bfbits(float f) {
  bf16 b = __float2bfloat16(f);
  return __builtin_bit_cast(short, b);
}

static __device__ __forceinline__ void gload16(const void* g, void* l) {
  __builtin_amdgcn_global_load_lds((const __attribute__((address_space(1))) void*)g,
                                   (__attribute__((address_space(3))) void*)l, 16, 0, 0);
}

// ---------------- GPTQ int4 dequant of one qword -> 8 bf16 ----------------
static __device__ __forceinline__ void dq8(const unsigned* __restrict__ qw,
                                           const unsigned* __restrict__ qz,
                                           const float* __restrict__ sc,
                                           bf16* __restrict__ wt, int N, int K, long tid) {
  int k8 = (int)(tid / N);
  int n  = (int)(tid % N);
  int g  = k8 >> 4;                      // (k8*8)/128
  unsigned q  = qw[tid];                 // qweight[k8][n]
  unsigned zq = qz[g * (N >> 3) + (n >> 3)];
  float z = (float)(((zq >> ((n & 7) * 4)) & 15u) + 1u);
  float s = sc[g * N + n];
  short8 o;
#pragma unroll
  for (int i = 0; i < 8; i++) {
    float w = (float)((q >> (4 * i)) & 15u);
    o[i] = bfbits((w - z) * s);
  }
  *(short8*)&wt[(size_t)n * K + (k8 << 3)] = o;
}

// ---------------- fused prep: rope table + cast + dequant(s) ----------------
// segments (all boundaries multiples of 256):
//   [0, 131072)              rope table [S][64] float2
//   [.., +2097152)           cast X fp32 -> bf16 (float4 granules)
//   [.., +6291456)           dequant W_qkv
//   [.., +2097152) if FULL   dequant W_o (separate region)
template<int FULL>
__global__ void k_prep(float2* __restrict__ rt, const float4* __restrict__ X,
                       short4v* __restrict__ Xb,
                       const unsigned* __restrict__ qwq, const unsigned* __restrict__ qzq,
                       const float* __restrict__ scq, bf16* __restrict__ Wq,
                       const unsigned* __restrict__ qwo, const unsigned* __restrict__ qzo,
                       const float* __restrict__ sco, bf16* __restrict__ Wo)
{
  long tid = (long)blockIdx.x * 256 + threadIdx.x;
  if (tid < 131072) {
    int s = (int)(tid >> 6), j = (int)(tid & 63);
    float inv = exp2f(-(float)j * (13.287712379549449f / 64.f)); // 10000^(-j/64)
    float a = (float)s * inv;
    rt[tid] = make_float2(cosf(a), sinf(a));
    return;
  }
  tid -= 131072;
  if (tid < 2097152) {
    float4 v = X[tid];
    short4v o = { bfbits(v.x), bfbits(v.y), bfbits(v.z), bfbits(v.w) };
    Xb[tid] = o;
    return;
  }
  tid -= 2097152;
  if (tid < 6291456) { dq8(qwq, qzq, scq, Wq, 12288, 4096, tid); return; }
  if constexpr (FULL) { tid -= 6291456; dq8(qwo, qzo, sco, Wo, 4096, 4096, tid); }
}

// standalone dequant (fallback when workspace too small for separate W_o)
__global__ void k_dequant(const unsigned* __restrict__ qw, const unsigned* __restrict__ qz,
                          const float* __restrict__ sc, bf16* __restrict__ wt,
                          int N, int K) {
  long tid = (long)blockIdx.x * 256 + threadIdx.x;
  if (tid >= (long)(K >> 3) * N) return;
  dq8(qw, qz, sc, wt, N, K, tid);
}

// ---------------- pipelined bf16 MFMA GEMM, BK=32, multi-block/CU ----------
// C[M,N] = A[M,K] @ Bt[N,K]^T.  BM x 128 tile, BK=32, NTHR threads
// (BM=256:512thr / BM=128:256thr), wave tile 64x64.  3 LDS buffers ->
// 2-3 blocks/CU.  Frag ds_reads prefetch tile+1 right after its publish
// barrier; 1 barrier + counted vmcnt per tile (never 0 mid-loop).
// Chunk swizzle c^((row>>1)&3), inverse on global source.
template<int EPI, int BM, int NTHR>
__global__ __launch_bounds__(NTHR, 4)
void k_gemm8(const bf16* __restrict__ A, const bf16* __restrict__ Bt, int K, int N,
             float* __restrict__ outf,
             bf16* __restrict__ Qv, bf16* __restrict__ Kv, bf16* __restrict__ VT,
             const float2* __restrict__ rope, int nby)
{
  constexpr int AE     = BM * 32;            // A elements per buffer
  constexpr int BLOADS = 512 / NTHR;         // B loads per thread (1 or 2)
  constexpr int SOPS   = 2 + BLOADS;         // VMEM ops per stage

  __shared__ __align__(16) char smem[3 * BM * 64 + 3 * 128 * 64];
  bf16* const sA = (bf16*)smem;                           // 3 x [BM][32]
  bf16* const sB = (bf16*)(smem + 3 * BM * 64);           // 3 x [128][32]

  const int t = threadIdx.x;
  const int wid = t >> 6, lane = t & 63;
  const int la = lane & 15, lb = lane >> 4;
  const int wr = wid >> 1, wc = wid & 1;

  const int nwg  = gridDim.x;
  const int bid  = blockIdx.x;
  const int wgid = (bid & 7) * (nwg >> 3) + (bid >> 3);   // bijective (nwg%8==0)
  const int by = wgid % nby, bx = wgid / nby;             // col-major: B-panel sharing
  const int m0 = by * BM, n0 = bx * 128;

  const int srow = t >> 2;
  const int scol = ((t & 3) ^ ((t >> 3) & 3)) * 8;        // element offset
  const bf16* gA = A  + (size_t)(m0 + srow) * K + scol;
  const bf16* gB = Bt + (size_t)(n0 + srow) * K + scol;

  const int NT = K >> 5;                                  // BK=32

  auto stage = [&](int tile, int buf) {
    const bf16* a = gA + tile * 32;
    gload16(a,                        sA + buf * AE + t * 8);
    gload16(a + (size_t)(BM / 2) * K, sA + buf * AE + AE / 2 + t * 8);
    const bf16* b = gB + tile * 32;
#pragma unroll
    for (int j = 0; j < BLOADS; j++)
      gload16(b + (size_t)(j * 64) * K, sB + buf * 4096 + j * 2048 + t * 8);
  };

  auto rdA = [&](short8 (&f)[4], const bf16* bufA) {
#pragma unroll
    for (int mf = 0; mf < 4; mf++) {
      int row = wr * 64 + mf * 16 + la;
      f[mf] = *(const short8*)((const char*)bufA + row * 64 + ((lb ^ ((row >> 1) & 3)) * 16));
    }
  };
  auto rdB = [&](short8 (&f)[4], const bf16* bufB) {
#pragma unroll
    for (int nf = 0; nf < 4; nf++) {
      int row = wc * 64 + nf * 16 + la;
      f[nf] = *(const short8*)((const char*)bufB + row * 64 + ((lb ^ ((row >> 1) & 3)) * 16));
    }
  };

  f32x4 acc[4][4] = {};
  short8 fa[4], fb[4];

  stage(0, 0); stage(1, 1);
  if constexpr (SOPS == 3) VMWAIT(3); else VMWAIT(4);     // tile 0 landed
  __builtin_amdgcn_s_barrier();
  rdA(fa, sA); rdB(fb, sB);                  // frags tile 0

  int b0 = 0, b1 = 1, b2 = 2;
  for (int tt = 0; tt < NT; tt++) {
    if (tt + 2 < NT) stage(tt + 2, b2);
    __builtin_amdgcn_s_setprio(1);
#pragma unroll
    for (int mf = 0; mf < 4; mf++)
#pragma unroll
      for (int nf = 0; nf < 4; nf++)
        acc[mf][nf] = MFMA16(fa[mf], fb[nf], acc[mf][nf]);
    __builtin_amdgcn_s_setprio(0);
    if (tt + 1 < NT) {
      if (tt + 2 < NT) { if constexpr (SOPS == 3) VMWAIT(3); else VMWAIT(4); }
      else VMWAIT(0);                                     // tile+1 landed
      __builtin_amdgcn_s_barrier();
      rdA(fa, sA + b1 * AE); rdB(fb, sB + b1 * 4096);
    }
    int tmp = b0; b0 = b1; b1 = b2; b2 = tmp;
  }

  if constexpr (EPI == 1) {
#pragma unroll
    for (int mf = 0; mf < 4; mf++)
#pragma unroll
      for (int nf = 0; nf < 4; nf++)
#pragma unroll
        for (int r = 0; r < 4; r++) {
          int row = m0 + wr * 64 + mf * 16 + lb * 4 + r;
          int col = n0 + wc * 64 + nf * 16 + la;
          outf[(size_t)row * N + col] = acc[mf][nf][r];
        }
  } else {
    const int typ = n0 >> 12;              // block = exactly one 128-col head
    const int h   = (n0 & 4095) >> 7;
    if (typ == 2) {
      bf16* dst = VT + (size_t)h * D * S;  // [d][s]
#pragma unroll
      for (int mf = 0; mf < 4; mf++)
#pragma unroll
        for (int nf = 0; nf < 4; nf++) {
          int d  = wc * 64 + nf * 16 + la;
          int s0 = m0 + wr * 64 + mf * 16 + lb * 4;
          short4v o = { bfbits(acc[mf][nf][0]), bfbits(acc[mf][nf][1]),
                        bfbits(acc[mf][nf][2]), bfbits(acc[mf][nf][3]) };
          *(short4v*)&dst[(size_t)d * S + s0] = o;
        }
    } else {
      // RoPE: exchange the BMx128 tile through LDS (now free)
      bf16* dst = (typ == 0 ? Qv : Kv) + (size_t)h * S * D;
      bf16* xs = (bf16*)smem;              // [BM][128] bf16
      __syncthreads();
#pragma unroll
      for (int mf = 0; mf < 4; mf++)
#pragma unroll
        for (int nf = 0; nf < 4; nf++)
#pragma unroll
          for (int r = 0; r < 4; r++)
            xs[(wr * 64 + mf * 16 + lb * 4 + r) * 128 + wc * 64 + nf * 16 + la] =
                __float2bfloat16(acc[mf][nf][r]);
      __syncthreads();
      constexpr int NW = BM * 64 / NTHR;   // d-pair items per thread
#pragma unroll 4
      for (int w = 0; w < NW; w++) {
        int idx = w * NTHR + t;            // BM rows x 64 d-pairs
        int row = idx >> 6, dp = idx & 63;
        float x  = __bfloat162float(xs[row * 128 + dp]);
        float xp = __bfloat162float(xs[row * 128 + dp + 64]);
        float2 cs = rope[(size_t)(m0 + row) * 64 + dp];
        dst[(size_t)(m0 + row) * D + dp]      = __float2bfloat16(x * cs.x - xp * cs.y);
        dst[(size_t)(m0 + row) * D + dp + 64] = __float2bfloat16(xp * cs.x + x * cs.y);
      }
    }
  }
}

// ---------------- causal flash attention, paired q-tiles + LDS KV pipeline ----
__device__ __forceinline__ void tile_step(
    const short8 (&qf)[4], f32x4 (&o)[8], float (&mrow)[4], float (&lrow)[4],
    int q0t, int kv0, const char* kld, const char* vld,
    bf16 (*Pw)[72], int la, int lb)
{
  const float smscale = 0.08838834764831845f;   // 1/sqrt(128)
  f32x4 sv[4] = {};
  __builtin_amdgcn_s_setprio(1);
#pragma unroll
  for (int ks = 0; ks < 4; ks++) {
#pragma unroll
    for (int kf = 0; kf < 4; kf++) {
      int row = kf * 16 + la;
      short8 kb = *(const short8*)(kld + row * 256 + ((ks * 64 + lb * 16) ^ ((row & 7) << 4)));
      sv[kf] = MFMA16(qf[ks], kb, sv[kf]);
    }
  }
  __builtin_amdgcn_s_setprio(0);
  const bool needmask = (kv0 + 63 > q0t);
#pragma unroll
  for (int kf = 0; kf < 4; kf++)
#pragma unroll
    for (int r = 0; r < 4; r++) {
      float v = sv[kf][r] * smscale;
      if (needmask && (kv0 + kf * 16 + la > q0t + lb * 4 + r)) v = -1e30f;
      sv[kf][r] = v;
    }
  float mnew[4], csc[4], rs[4];
#pragma unroll
  for (int r = 0; r < 4; r++)
    mnew[r] = fmaxf(fmaxf(sv[0][r], sv[1][r]), fmaxf(sv[2][r], sv[3][r]));
#pragma unroll
  for (int off = 1; off < 16; off <<= 1)
#pragma unroll
    for (int r = 0; r < 4; r++) mnew[r] = fmaxf(mnew[r], __shfl_xor(mnew[r], off));
#pragma unroll
  for (int r = 0; r < 4; r++) {
    float mt = fmaxf(mrow[r], mnew[r]);
    csc[r] = __expf(mrow[r] - mt);
    mrow[r] = mt;
    rs[r] = 0.f;
  }
#pragma unroll
  for (int kf = 0; kf < 4; kf++)
#pragma unroll
    for (int r = 0; r < 4; r++) {
      float p = __expf(sv[kf][r] - mrow[r]);
      sv[kf][r] = p;
      rs[r] += p;
    }
#pragma unroll
  for (int off = 1; off < 16; off <<= 1)
#pragma unroll
    for (int r = 0; r < 4; r++) rs[r] += __shfl_xor(rs[r], off);
#pragma unroll
  for (int r = 0; r < 4; r++) lrow[r] = lrow[r] * csc[r] + rs[r];
#pragma unroll
  for (int df = 0; df < 8; df++)
#pragma unroll
    for (int r = 0; r < 4; r++) o[df][r] *= csc[r];
#pragma unroll
  for (int kf = 0; kf < 4; kf++)
#pragma unroll
    for (int r = 0; r < 4; r++)
      Pw[lb * 4 + r][kf * 16 + la] = __float2bfloat16(sv[kf][r]);
  asm volatile("s_waitcnt lgkmcnt(0)" ::: "memory");
  __builtin_amdgcn_sched_barrier(0);
  short8 pa0 = *(const short8*)&Pw[la][lb * 8];
  short8 pa1 = *(const short8*)&Pw[la][32 + lb * 8];
  __builtin_amdgcn_s_setprio(1);
#pragma unroll
  for (int df = 0; df < 8; df++) {
    int d = df * 16 + la;
    short8 vb0 = *(const short8*)(vld + d * 128 + ((lb * 16) ^ ((d & 7) << 4)));
    o[df] = MFMA16(pa0, vb0, o[df]);
    short8 vb1 = *(const short8*)(vld + d * 128 + ((64 + lb * 16) ^ ((d & 7) << 4)));
    o[df] = MFMA16(pa1, vb1, o[df]);
  }
  __builtin_amdgcn_s_setprio(0);
}

__global__ __launch_bounds__(256, 2)
void k_attn(const bf16* __restrict__ Qv, const bf16* __restrict__ Kvp,
            const bf16* __restrict__ VT, bf16* __restrict__ AO)
{
  __shared__ __align__(16) char kvs[2][2][16384];   // [dbuf][K/V]
  __shared__ __align__(16) bf16 P[4][16][72];
  const int t = threadIdx.x, wid = t >> 6, lane = t & 63;
  const int la = lane & 15, lb = lane >> 4;
  // XCD-locality swizzle: all 16 q-pair blocks of a head share one XCD.
  const int bid = blockIdx.x;                        // 0..511
  const int h  = ((bid & 7) << 2) | ((bid >> 3) & 3);
  const int ip = bid >> 5;                           // 0..15
  const int tA = ip, tB = 31 - ip;
  const int q0A = tA * 64 + wid * 16, q0B = tB * 64 + wid * 16;
  const bf16* Qh = Qv  + (size_t)h * S * D;
  const bf16* Kh = Kvp + (size_t)h * S * D;
  const bf16* Vh = VT  + (size_t)h * D * S;

  short8 qfA[4], qfB[4];
#pragma unroll
  for (int ks = 0; ks < 4; ks++) {
    qfA[ks] = *(const short8*)&Qh[(size_t)(q0A + la) * D + ks * 32 + lb * 8];
    qfB[ks] = *(const short8*)&Qh[(size_t)(q0B + la) * D + ks * 32 + lb * 8];
  }

  f32x4 oA[8] = {}, oB[8] = {};
  float mA[4] = {-1e30f, -1e30f, -1e30f, -1e30f}, lA[4] = {};
  float mB[4] = {-1e30f, -1e30f, -1e30f, -1e30f}, lB[4] = {};

  auto stage = [&](int buf, int kv0) {
#pragma unroll
    for (int i = 0; i < 4; i++) {
      int off = i * 4096 + wid * 1024 + lane * 16;
      int krow = off >> 8, kcol = off & 255;
      const char* ksrc = (const char*)Kh + (size_t)(kv0 + krow) * 256 + (kcol ^ ((krow & 7) << 4));
      gload16(ksrc, &kvs[buf][0][i * 4096 + wid * 1024]);
      int vrow = off >> 7, vcol = off & 127;
      const char* vsrc = (const char*)Vh + (size_t)vrow * (S * 2) + kv0 * 2 + (vcol ^ ((vrow & 7) << 4));
      gload16(vsrc, &kvs[buf][1][i * 4096 + wid * 1024]);
    }
  };

  stage(0, 0);
  __syncthreads();

  const int last = tB;
  for (int kt = 0; kt <= last; kt++) {
    int cur = kt & 1;
    if (kt < last) stage(cur ^ 1, (kt + 1) * 64);
    const char* kld = kvs[cur][0];
    const char* vld = kvs[cur][1];
    int kv0 = kt * 64;
    if (kt <= tA) tile_step(qfA, oA, mA, lA, q0A, kv0, kld, vld, P[wid], la, lb);
    tile_step(qfB, oB, mB, lB, q0B, kv0, kld, vld, P[wid], la, lb);
    __syncthreads();
  }

#pragma unroll
  for (int r = 0; r < 4; r++) { mA[r] = 1.f / lA[r]; mB[r] = 1.f / lB[r]; }
#pragma unroll
  for (int df = 0; df < 8; df++)
#pragma unroll
    for (int r = 0; r < 4; r++) {
      int d = df * 16 + la;
      AO[(size_t)(q0A + lb * 4 + r) * H + h * D + d] = __float2bfloat16(oA[df][r] * mA[r]);
      AO[(size_t)(q0B + lb * 4 + r) * H + h * D + d] = __float2bfloat16(oB[df][r] * mB[r]);
    }
}

extern "C" void kernel_launch(void* const* d_in, const int* in_sizes, int n_in,
                              void* d_out, int out_size, void* d_ws, size_t ws_size,
                              hipStream_t stream) {
  const float*    X      = (const float*)d_in[0];
  const unsigned* qw_qkv = (const unsigned*)d_in[1];
  const unsigned* qz_qkv = (const unsigned*)d_in[2];
  const float*    sc_qkv = (const float*)d_in[3];
  const unsigned* qw_o   = (const unsigned*)d_in[4];
  const unsigned* qz_o   = (const unsigned*)d_in[5];
  const float*    sc_o   = (const float*)d_in[6];
  float* out = (float*)d_out;

  if (ws_size < 168820736ULL) return;
  char* ws = (char*)d_ws;
  bf16*   Wt = (bf16*)(ws);
  bf16*   Xb = (bf16*)(ws + 100663296);
  bf16*   Qv = (bf16*)(ws + 117440512);
  bf16*   Kv = (bf16*)(ws + 134217728);
  bf16*   VT = (bf16*)(ws + 150994944);
  float2* rt = (float2*)(ws + 167772160);
  bf16*   AO = Xb;

  const bool full = ws_size >= 202375168ULL;       // room for separate W_o
  bf16* Wo = full ? (bf16*)(ws + 168820736) : Wt;  // fallback: reuse Wt later

  if (full) {
    k_prep<1><<<41472, 256, 0, stream>>>(rt, (const float4*)X, (short4v*)Xb,
                                         qw_qkv, qz_qkv, sc_qkv, Wt,
                                         qw_o, qz_o, sc_o, Wo);
  } else {
    k_prep<0><<<33280, 256, 0, stream>>>(rt, (const float4*)X, (short4v*)Xb,
                                         qw_qkv, qz_qkv, sc_qkv, Wt,
                                         qw_o, qz_o, sc_o, nullptr);
  }
  k_gemm8<0, 128, 256><<<1536, 256, 0, stream>>>(Xb, Wt, 4096, 12288, nullptr,
                                                 Qv, Kv, VT, rt, 16);
  if (!full)
    k_dequant<<<(512 * 4096) / 256, 256, 0, stream>>>(qw_o, qz_o, sc_o, Wt, 4096, 4096);
  k_attn<<<512, 256, 0, stream>>>(Qv, Kv, VT, AO);
  k_gemm8<1, 128, 256><<<512, 256, 0, stream>>>(AO, Wo, 4096, 4096, out,
                                                nullptr, nullptr, nullptr, nullptr, 16);
}

// Round 14
// 432.668 us; speedup vs baseline: 1.0784x; 1.0784x over previous
//
#include <hip/hip_runtime.h>
#include <hip/hip_bf16.h>
#include <cstdint>
#include <cstddef>

using bf16 = __hip_bfloat16;
typedef __attribute__((ext_vector_type(8))) short short8;
typedef __attribute__((ext_vector_type(4))) short short4v;
typedef __attribute__((ext_vector_type(4))) float f32x4;

#define MFMA16(a,b,c) __builtin_amdgcn_mfma_f32_16x16x32_bf16((a),(b),(c),0,0,0)
#define VMWAIT(n) asm volatile("s_waitcnt vmcnt(" #n ")" ::: "memory")

constexpr int S  = 2048;
constexpr int H  = 4096;
constexpr int D  = 128;

static __device__ __forceinline__ short bfbits(float f) {
  bf16 b = __float2bfloat16(f);
  return __builtin_bit_cast(short, b);
}

static __device__ __forceinline__ void gload16(const void* g, void* l) {
  __builtin_amdgcn_global_load_lds((const __attribute__((address_space(1))) void*)g,
                                   (__attribute__((address_space(3))) void*)l, 16, 0, 0);
}

// ---------------- GPTQ int4 dequant of one qword -> 8 bf16 ----------------
static __device__ __forceinline__ void dq8(const unsigned* __restrict__ qw,
                                           const unsigned* __restrict__ qz,
                                           const float* __restrict__ sc,
                                           bf16* __restrict__ wt, int N, int K, long tid) {
  int k8 = (int)(tid / N);
  int n  = (int)(tid % N);
  int g  = k8 >> 4;                      // (k8*8)/128
  unsigned q  = qw[tid];                 // qweight[k8][n]
  unsigned zq = qz[g * (N >> 3) + (n >> 3)];
  float z = (float)(((zq >> ((n & 7) * 4)) & 15u) + 1u);
  float s = sc[g * N + n];
  short8 o;
#pragma unroll
  for (int i = 0; i < 8; i++) {
    float w = (float)((q >> (4 * i)) & 15u);
    o[i] = bfbits((w - z) * s);
  }
  *(short8*)&wt[(size_t)n * K + (k8 << 3)] = o;
}

// ---------------- fused prep: rope table + cast + dequant(s) ----------------
template<int FULL>
__global__ void k_prep(float2* __restrict__ rt, const float4* __restrict__ X,
                       short4v* __restrict__ Xb,
                       const unsigned* __restrict__ qwq, const unsigned* __restrict__ qzq,
                       const float* __restrict__ scq, bf16* __restrict__ Wq,
                       const unsigned* __restrict__ qwo, const unsigned* __restrict__ qzo,
                       const float* __restrict__ sco, bf16* __restrict__ Wo)
{
  long tid = (long)blockIdx.x * 256 + threadIdx.x;
  if (tid < 131072) {
    int s = (int)(tid >> 6), j = (int)(tid & 63);
    float inv = exp2f(-(float)j * (13.287712379549449f / 64.f)); // 10000^(-j/64)
    float a = (float)s * inv;
    rt[tid] = make_float2(cosf(a), sinf(a));
    return;
  }
  tid -= 131072;
  if (tid < 2097152) {
    float4 v = X[tid];
    short4v o = { bfbits(v.x), bfbits(v.y), bfbits(v.z), bfbits(v.w) };
    Xb[tid] = o;
    return;
  }
  tid -= 2097152;
  if (tid < 6291456) { dq8(qwq, qzq, scq, Wq, 12288, 4096, tid); return; }
  if constexpr (FULL) { tid -= 6291456; dq8(qwo, qzo, sco, Wo, 4096, 4096, tid); }
}

// standalone dequant (fallback when workspace too small for separate W_o)
__global__ void k_dequant(const unsigned* __restrict__ qw, const unsigned* __restrict__ qz,
                          const float* __restrict__ sc, bf16* __restrict__ wt,
                          int N, int K) {
  long tid = (long)blockIdx.x * 256 + threadIdx.x;
  if (tid >= (long)(K >> 3) * N) return;
  dq8(qw, qz, sc, wt, N, K, tid);
}

// ---------------- pipelined bf16 MFMA GEMM, BK=32, multi-block/CU ----------
// C[M,N] = A[M,K] @ Bt[N,K]^T.  BM x 128 tile, BK=32, NTHR threads
// (BM=256:512thr / BM=128:256thr), wave tile 64x64.  3 LDS buffers ->
// 2-3 blocks/CU.  Frag ds_reads prefetch tile+1 right after its publish
// barrier; 1 barrier + counted vmcnt per tile (never 0 mid-loop).
// Chunk swizzle c^((row>>1)&3), inverse on global source.
template<int EPI, int BM, int NTHR>
__global__ __launch_bounds__(NTHR, 4)
void k_gemm8(const bf16* __restrict__ A, const bf16* __restrict__ Bt, int K, int N,
             float* __restrict__ outf,
             bf16* __restrict__ Qv, bf16* __restrict__ Kv, bf16* __restrict__ VT,
             const float2* __restrict__ rope, int nby)
{
  constexpr int AE     = BM * 32;            // A elements per buffer
  constexpr int BLOADS = 512 / NTHR;         // B loads per thread (1 or 2)
  constexpr int SOPS   = 2 + BLOADS;         // VMEM ops per stage

  __shared__ __align__(16) char smem[3 * BM * 64 + 3 * 128 * 64];
  bf16* const sA = (bf16*)smem;                           // 3 x [BM][32]
  bf16* const sB = (bf16*)(smem + 3 * BM * 64);           // 3 x [128][32]

  const int t = threadIdx.x;
  const int wid = t >> 6, lane = t & 63;
  const int la = lane & 15, lb = lane >> 4;
  const int wr = wid >> 1, wc = wid & 1;

  const int nwg  = gridDim.x;
  const int bid  = blockIdx.x;
  const int wgid = (bid & 7) * (nwg >> 3) + (bid >> 3);   // bijective (nwg%8==0)
  const int by = wgid % nby, bx = wgid / nby;             // col-major: B-panel sharing
  const int m0 = by * BM, n0 = bx * 128;

  const int srow = t >> 2;
  const int scol = ((t & 3) ^ ((t >> 3) & 3)) * 8;        // element offset
  const bf16* gA = A  + (size_t)(m0 + srow) * K + scol;
  const bf16* gB = Bt + (size_t)(n0 + srow) * K + scol;

  const int NT = K >> 5;                                  // BK=32

  auto stage = [&](int tile, int buf) {
    const bf16* a = gA + tile * 32;
    gload16(a,                        sA + buf * AE + t * 8);
    gload16(a + (size_t)(BM / 2) * K, sA + buf * AE + AE / 2 + t * 8);
    const bf16* b = gB + tile * 32;
#pragma unroll
    for (int j = 0; j < BLOADS; j++)
      gload16(b + (size_t)(j * 64) * K, sB + buf * 4096 + j * 2048 + t * 8);
  };

  auto rdA = [&](short8 (&f)[4], const bf16* bufA) {
#pragma unroll
    for (int mf = 0; mf < 4; mf++) {
      int row = wr * 64 + mf * 16 + la;
      f[mf] = *(const short8*)((const char*)bufA + row * 64 + ((lb ^ ((row >> 1) & 3)) * 16));
    }
  };
  auto rdB = [&](short8 (&f)[4], const bf16* bufB) {
#pragma unroll
    for (int nf = 0; nf < 4; nf++) {
      int row = wc * 64 + nf * 16 + la;
      f[nf] = *(const short8*)((const char*)bufB + row * 64 + ((lb ^ ((row >> 1) & 3)) * 16));
    }
  };

  f32x4 acc[4][4] = {};
  short8 fa[4], fb[4];

  stage(0, 0); stage(1, 1);
  if constexpr (SOPS == 3) VMWAIT(3); else VMWAIT(4);     // tile 0 landed
  __builtin_amdgcn_s_barrier();
  rdA(fa, sA); rdB(fb, sB);                  // frags tile 0

  int b0 = 0, b1 = 1, b2 = 2;
  for (int tt = 0; tt < NT; tt++) {
    if (tt + 2 < NT) stage(tt + 2, b2);
    __builtin_amdgcn_s_setprio(1);
#pragma unroll
    for (int mf = 0; mf < 4; mf++)
#pragma unroll
      for (int nf = 0; nf < 4; nf++)
        acc[mf][nf] = MFMA16(fa[mf], fb[nf], acc[mf][nf]);
    __builtin_amdgcn_s_setprio(0);
    if (tt + 1 < NT) {
      if (tt + 2 < NT) { if constexpr (SOPS == 3) VMWAIT(3); else VMWAIT(4); }
      else VMWAIT(0);                                     // tile+1 landed
      __builtin_amdgcn_s_barrier();
      rdA(fa, sA + b1 * AE); rdB(fb, sB + b1 * 4096);
    }
    int tmp = b0; b0 = b1; b1 = b2; b2 = tmp;
  }

  if constexpr (EPI == 1) {
#pragma unroll
    for (int mf = 0; mf < 4; mf++)
#pragma unroll
      for (int nf = 0; nf < 4; nf++)
#pragma unroll
        for (int r = 0; r < 4; r++) {
          int row = m0 + wr * 64 + mf * 16 + lb * 4 + r;
          int col = n0 + wc * 64 + nf * 16 + la;
          outf[(size_t)row * N + col] = acc[mf][nf][r];
        }
  } else {
    const int typ = n0 >> 12;              // block = exactly one 128-col head
    const int h   = (n0 & 4095) >> 7;
    if (typ == 2) {
      bf16* dst = VT + (size_t)h * D * S;  // [d][s]
#pragma unroll
      for (int mf = 0; mf < 4; mf++)
#pragma unroll
        for (int nf = 0; nf < 4; nf++) {
          int d  = wc * 64 + nf * 16 + la;
          int s0 = m0 + wr * 64 + mf * 16 + lb * 4;
          short4v o = { bfbits(acc[mf][nf][0]), bfbits(acc[mf][nf][1]),
                        bfbits(acc[mf][nf][2]), bfbits(acc[mf][nf][3]) };
          *(short4v*)&dst[(size_t)d * S + s0] = o;
        }
    } else {
      // RoPE: exchange the BMx128 tile through LDS (now free)
      bf16* dst = (typ == 0 ? Qv : Kv) + (size_t)h * S * D;
      bf16* xs = (bf16*)smem;              // [BM][128] bf16
      __syncthreads();
#pragma unroll
      for (int mf = 0; mf < 4; mf++)
#pragma unroll
        for (int nf = 0; nf < 4; nf++)
#pragma unroll
          for (int r = 0; r < 4; r++)
            xs[(wr * 64 + mf * 16 + lb * 4 + r) * 128 + wc * 64 + nf * 16 + la] =
                __float2bfloat16(acc[mf][nf][r]);
      __syncthreads();
      constexpr int NW = BM * 64 / NTHR;   // d-pair items per thread
#pragma unroll 4
      for (int w = 0; w < NW; w++) {
        int idx = w * NTHR + t;            // BM rows x 64 d-pairs
        int row = idx >> 6, dp = idx & 63;
        float x  = __bfloat162float(xs[row * 128 + dp]);
        float xp = __bfloat162float(xs[row * 128 + dp + 64]);
        float2 cs = rope[(size_t)(m0 + row) * 64 + dp];
        dst[(size_t)(m0 + row) * D + dp]      = __float2bfloat16(x * cs.x - xp * cs.y);
        dst[(size_t)(m0 + row) * D + dp + 64] = __float2bfloat16(xp * cs.x + x * cs.y);
      }
    }
  }
}

// ---------------- causal flash attention, paired q-tiles + LDS KV pipeline ----
__device__ __forceinline__ void tile_step(
    const short8 (&qf)[4], f32x4 (&o)[8], float (&mrow)[4], float (&lrow)[4],
    int q0t, int kv0, const char* kld, const char* vld,
    bf16 (*Pw)[72], int la, int lb)
{
  const float smscale = 0.08838834764831845f;   // 1/sqrt(128)
  f32x4 sv[4] = {};
  __builtin_amdgcn_s_setprio(1);
#pragma unroll
  for (int ks = 0; ks < 4; ks++) {
#pragma unroll
    for (int kf = 0; kf < 4; kf++) {
      int row = kf * 16 + la;
      short8 kb = *(const short8*)(kld + row * 256 + ((ks * 64 + lb * 16) ^ ((row & 7) << 4)));
      sv[kf] = MFMA16(qf[ks], kb, sv[kf]);
    }
  }
  __builtin_amdgcn_s_setprio(0);
  const bool needmask = (kv0 + 63 > q0t);
#pragma unroll
  for (int kf = 0; kf < 4; kf++)
#pragma unroll
    for (int r = 0; r < 4; r++) {
      float v = sv[kf][r] * smscale;
      if (needmask && (kv0 + kf * 16 + la > q0t + lb * 4 + r)) v = -1e30f;
      sv[kf][r] = v;
    }
  float mnew[4], csc[4], rs[4];
#pragma unroll
  for (int r = 0; r < 4; r++)
    mnew[r] = fmaxf(fmaxf(sv[0][r], sv[1][r]), fmaxf(sv[2][r], sv[3][r]));
#pragma unroll
  for (int off = 1; off < 16; off <<= 1)
#pragma unroll
    for (int r = 0; r < 4; r++) mnew[r] = fmaxf(mnew[r], __shfl_xor(mnew[r], off));
#pragma unroll
  for (int r = 0; r < 4; r++) {
    float mt = fmaxf(mrow[r], mnew[r]);
    csc[r] = __expf(mrow[r] - mt);
    mrow[r] = mt;
    rs[r] = 0.f;
  }
#pragma unroll
  for (int kf = 0; kf < 4; kf++)
#pragma unroll
    for (int r = 0; r < 4; r++) {
      float p = __expf(sv[kf][r] - mrow[r]);
      sv[kf][r] = p;
      rs[r] += p;
    }
#pragma unroll
  for (int off = 1; off < 16; off <<= 1)
#pragma unroll
    for (int r = 0; r < 4; r++) rs[r] += __shfl_xor(rs[r], off);
#pragma unroll
  for (int r = 0; r < 4; r++) lrow[r] = lrow[r] * csc[r] + rs[r];
#pragma unroll
  for (int df = 0; df < 8; df++)
#pragma unroll
    for (int r = 0; r < 4; r++) o[df][r] *= csc[r];
#pragma unroll
  for (int kf = 0; kf < 4; kf++)
#pragma unroll
    for (int r = 0; r < 4; r++)
      Pw[lb * 4 + r][kf * 16 + la] = __float2bfloat16(sv[kf][r]);
  asm volatile("s_waitcnt lgkmcnt(0)" ::: "memory");
  __builtin_amdgcn_sched_barrier(0);
  short8 pa0 = *(const short8*)&Pw[la][lb * 8];
  short8 pa1 = *(const short8*)&Pw[la][32 + lb * 8];
  __builtin_amdgcn_s_setprio(1);
#pragma unroll
  for (int df = 0; df < 8; df++) {
    int d = df * 16 + la;
    short8 vb0 = *(const short8*)(vld + d * 128 + ((lb * 16) ^ ((d & 7) << 4)));
    o[df] = MFMA16(pa0, vb0, o[df]);
    short8 vb1 = *(const short8*)(vld + d * 128 + ((64 + lb * 16) ^ ((d & 7) << 4)));
    o[df] = MFMA16(pa1, vb1, o[df]);
  }
  __builtin_amdgcn_s_setprio(0);
}

__global__ __launch_bounds__(256, 2)
void k_attn(const bf16* __restrict__ Qv, const bf16* __restrict__ Kvp,
            const bf16* __restrict__ VT, bf16* __restrict__ AO)
{
  __shared__ __align__(16) char kvs[2][2][16384];   // [dbuf][K/V]
  __shared__ __align__(16) bf16 P[4][16][72];
  const int t = threadIdx.x, wid = t >> 6, lane = t & 63;
  const int la = lane & 15, lb = lane >> 4;
  // XCD-locality swizzle: all 16 q-pair blocks of a head share one XCD.
  const int bid = blockIdx.x;                        // 0..511
  const int h  = ((bid & 7) << 2) | ((bid >> 3) & 3);
  const int ip = bid >> 5;                           // 0..15
  const int tA = ip, tB = 31 - ip;
  const int q0A = tA * 64 + wid * 16, q0B = tB * 64 + wid * 16;
  const bf16* Qh = Qv  + (size_t)h * S * D;
  const bf16* Kh = Kvp + (size_t)h * S * D;
  const bf16* Vh = VT  + (size_t)h * D * S;

  short8 qfA[4], qfB[4];
#pragma unroll
  for (int ks = 0; ks < 4; ks++) {
    qfA[ks] = *(const short8*)&Qh[(size_t)(q0A + la) * D + ks * 32 + lb * 8];
    qfB[ks] = *(const short8*)&Qh[(size_t)(q0B + la) * D + ks * 32 + lb * 8];
  }

  f32x4 oA[8] = {}, oB[8] = {};
  float mA[4] = {-1e30f, -1e30f, -1e30f, -1e30f}, lA[4] = {};
  float mB[4] = {-1e30f, -1e30f, -1e30f, -1e30f}, lB[4] = {};

  auto stage = [&](int buf, int kv0) {
#pragma unroll
    for (int i = 0; i < 4; i++) {
      int off = i * 4096 + wid * 1024 + lane * 16;
      int krow = off >> 8, kcol = off & 255;
      const char* ksrc = (const char*)Kh + (size_t)(kv0 + krow) * 256 + (kcol ^ ((krow & 7) << 4));
      gload16(ksrc, &kvs[buf][0][i * 4096 + wid * 1024]);
      int vrow = off >> 7, vcol = off & 127;
      const char* vsrc = (const char*)Vh + (size_t)vrow * (S * 2) + kv0 * 2 + (vcol ^ ((vrow & 7) << 4));
      gload16(vsrc, &kvs[buf][1][i * 4096 + wid * 1024]);
    }
  };

  stage(0, 0);
  __syncthreads();

  const int last = tB;
  for (int kt = 0; kt <= last; kt++) {
    int cur = kt & 1;
    if (kt < last) stage(cur ^ 1, (kt + 1) * 64);
    const char* kld = kvs[cur][0];
    const char* vld = kvs[cur][1];
    int kv0 = kt * 64;
    if (kt <= tA) tile_step(qfA, oA, mA, lA, q0A, kv0, kld, vld, P[wid], la, lb);
    tile_step(qfB, oB, mB, lB, q0B, kv0, kld, vld, P[wid], la, lb);
    __syncthreads();
  }

#pragma unroll
  for (int r = 0; r < 4; r++) { mA[r] = 1.f / lA[r]; mB[r] = 1.f / lB[r]; }
#pragma unroll
  for (int df = 0; df < 8; df++)
#pragma unroll
    for (int r = 0; r < 4; r++) {
      int d = df * 16 + la;
      AO[(size_t)(q0A + lb * 4 + r) * H + h * D + d] = __float2bfloat16(oA[df][r] * mA[r]);
      AO[(size_t)(q0B + lb * 4 + r) * H + h * D + d] = __float2bfloat16(oB[df][r] * mB[r]);
    }
}

extern "C" void kernel_launch(void* const* d_in, const int* in_sizes, int n_in,
                              void* d_out, int out_size, void* d_ws, size_t ws_size,
                              hipStream_t stream) {
  const float*    X      = (const float*)d_in[0];
  const unsigned* qw_qkv = (const unsigned*)d_in[1];
  const unsigned* qz_qkv = (const unsigned*)d_in[2];
  const float*    sc_qkv = (const float*)d_in[3];
  const unsigned* qw_o   = (const unsigned*)d_in[4];
  const unsigned* qz_o   = (const unsigned*)d_in[5];
  const float*    sc_o   = (const float*)d_in[6];
  float* out = (float*)d_out;

  if (ws_size < 168820736ULL) return;
  char* ws = (char*)d_ws;
  bf16*   Wt = (bf16*)(ws);
  bf16*   Xb = (bf16*)(ws + 100663296);
  bf16*   Qv = (bf16*)(ws + 117440512);
  bf16*   Kv = (bf16*)(ws + 134217728);
  bf16*   VT = (bf16*)(ws + 150994944);
  float2* rt = (float2*)(ws + 167772160);
  bf16*   AO = Xb;

  const bool full = ws_size >= 202375168ULL;       // room for separate W_o
  bf16* Wo = full ? (bf16*)(ws + 168820736) : Wt;  // fallback: reuse Wt later

  if (full) {
    k_prep<1><<<41472, 256, 0, stream>>>(rt, (const float4*)X, (short4v*)Xb,
                                         qw_qkv, qz_qkv, sc_qkv, Wt,
                                         qw_o, qz_o, sc_o, Wo);
  } else {
    k_prep<0><<<33280, 256, 0, stream>>>(rt, (const float4*)X, (short4v*)Xb,
                                         qw_qkv, qz_qkv, sc_qkv, Wt,
                                         qw_o, qz_o, sc_o, nullptr);
  }
  k_gemm8<0, 256, 512><<<768, 512, 0, stream>>>(Xb, Wt, 4096, 12288, nullptr,
                                                Qv, Kv, VT, rt, 8);
  if (!full)
    k_dequant<<<(512 * 4096) / 256, 256, 0, stream>>>(qw_o, qz_o, sc_o, Wt, 4096, 4096);
  k_attn<<<512, 256, 0, stream>>>(Qv, Kv, VT, AO);
  k_gemm8<1, 128, 256><<<512, 256, 0, stream>>>(AO, Wo, 4096, 4096, out,
                                                nullptr, nullptr, nullptr, nullptr, 16);
}